// Round 3
// baseline (1051.219 us; speedup 1.0000x reference)
//
#include <hip/hip_runtime.h>

#define B_ 8
#define T_ 2048
#define D_ 768
#define H_ 12
#define HS_ 64
#define LN_EPS 1e-5f
#define CHUNK 32

typedef __attribute__((ext_vector_type(8))) short bf16x8;
typedef __attribute__((ext_vector_type(4))) float f32x4;

__device__ __forceinline__ ushort f2bf(float f) {
  unsigned u = __builtin_bit_cast(unsigned, f);
  unsigned r = (u + 0x7FFFu + ((u >> 16) & 1u)) >> 16;
  return (ushort)r;
}
__device__ __forceinline__ float bf2f(ushort u) {
  return __builtin_bit_cast(float, ((unsigned)u) << 16);
}

// ---------------- canary: zero d_out if workspace too small ----------------
__global__ __launch_bounds__(256) void zero_out_kernel(float* __restrict__ out, int n) {
  for (int i = blockIdx.x * 256 + threadIdx.x; i < n; i += gridDim.x * 256)
    out[i] = 0.f;
}

// ---------------- weight cast: one (768x768) fp32 -> bf16 ----------------
__global__ __launch_bounds__(256) void cast_w_kernel(
    const float* __restrict__ src, ushort* __restrict__ dst) {
  int idx = (blockIdx.x * 256 + threadIdx.x) * 4;
  float4 v = *reinterpret_cast<const float4*>(src + idx);
  ushort4 o;
  o.x = f2bf(v.x); o.y = f2bf(v.y); o.z = f2bf(v.z); o.w = f2bf(v.w);
  *reinterpret_cast<ushort4*>(dst + idx) = o;
}

// ---------------- LayerNorm: one wave per row of 768, out bf16 ----------------
__global__ __launch_bounds__(256) void ln_kernel(
    const float* __restrict__ x, const float* __restrict__ gamma,
    const float* __restrict__ beta, ushort* __restrict__ xn) {
  const int wv = threadIdx.x >> 6;
  const int lane = threadIdx.x & 63;
  const int row = blockIdx.x * 4 + wv;
  const float* xr = x + (size_t)row * D_;
  float4 a[3];
#pragma unroll
  for (int s = 0; s < 3; ++s)
    a[s] = *reinterpret_cast<const float4*>(xr + s * 256 + lane * 4);
  float sum = 0.f;
#pragma unroll
  for (int s = 0; s < 3; ++s) sum += a[s].x + a[s].y + a[s].z + a[s].w;
#pragma unroll
  for (int off = 32; off; off >>= 1) sum += __shfl_xor(sum, off);
  float mu = sum * (1.f / 768.f);
  float vs = 0.f;
#pragma unroll
  for (int s = 0; s < 3; ++s) {
    float dx = a[s].x - mu, dy = a[s].y - mu, dz = a[s].z - mu, dw = a[s].w - mu;
    vs += dx * dx + dy * dy + dz * dz + dw * dw;
  }
#pragma unroll
  for (int off = 32; off; off >>= 1) vs += __shfl_xor(vs, off);
  float rs = rsqrtf(vs * (1.f / 768.f) + LN_EPS);
  ushort* orow = xn + (size_t)row * D_;
#pragma unroll
  for (int s = 0; s < 3; ++s) {
    int col = s * 256 + lane * 4;
    float4 g = *reinterpret_cast<const float4*>(gamma + col);
    float4 bb = *reinterpret_cast<const float4*>(beta + col);
    ushort4 o;
    o.x = f2bf((a[s].x - mu) * rs * g.x + bb.x);
    o.y = f2bf((a[s].y - mu) * rs * g.y + bb.y);
    o.z = f2bf((a[s].z - mu) * rs * g.z + bb.z);
    o.w = f2bf((a[s].w - mu) * rs * g.w + bb.w);
    *reinterpret_cast<ushort4*>(orow + col) = o;
  }
}

// ---------------- bf16 MFMA GEMM: C[m,n] = sum_k A[m,k]*W[n,k] ----------------
// M=16384, N=768, K=768.
// modes: 0 fp32 plain, 2 bf16 plain, 3 fp32 decay=1-sigmoid(val+bias), 4 bf16 sigmoid
__global__ __launch_bounds__(256) void gemm_bt(
    const ushort* __restrict__ A, const ushort* __restrict__ W,
    void* __restrict__ Cout, const float* __restrict__ bias, int mode) {
  constexpr int K = 768, N = 768;
  __shared__ __align__(16) ushort As[128 * 64];
  __shared__ __align__(16) ushort Bs[128 * 64];
  const int tid = threadIdx.x;
  const int wv = tid >> 6, lane = tid & 63;
  const int m0 = blockIdx.x * 128, n0 = blockIdx.y * 128;
  const int wr = wv >> 1, wc = wv & 1;
  const int fr = lane & 15, fq = lane >> 4;
  const int srow = tid >> 3;          // staging row 0..31
  const int scol = (tid & 7) * 8;     // staging col (ushort)
  f32x4 zero = {0.f, 0.f, 0.f, 0.f};
  f32x4 acc[4][4];
#pragma unroll
  for (int mi = 0; mi < 4; ++mi)
#pragma unroll
    for (int ni = 0; ni < 4; ++ni) acc[mi][ni] = zero;

  for (int k0 = 0; k0 < K; k0 += 64) {
    bf16x8 ra[4], rb[4];
#pragma unroll
    for (int it = 0; it < 4; ++it) {
      int row = it * 32 + srow;
      ra[it] = *reinterpret_cast<const bf16x8*>(A + (size_t)(m0 + row) * K + k0 + scol);
      rb[it] = *reinterpret_cast<const bf16x8*>(W + (size_t)(n0 + row) * K + k0 + scol);
    }
#pragma unroll
    for (int it = 0; it < 4; ++it) {
      *reinterpret_cast<bf16x8*>(As + it * 2048 + tid * 8) = ra[it];
      *reinterpret_cast<bf16x8*>(Bs + it * 2048 + tid * 8) = rb[it];
    }
    __syncthreads();
#pragma unroll
    for (int kk = 0; kk < 2; ++kk) {
      bf16x8 af[4], bfr[4];
#pragma unroll
      for (int mi = 0; mi < 4; ++mi)
        af[mi] = *reinterpret_cast<const bf16x8*>(
            As + (wr * 64 + mi * 16 + fr) * 64 + kk * 32 + fq * 8);
#pragma unroll
      for (int ni = 0; ni < 4; ++ni)
        bfr[ni] = *reinterpret_cast<const bf16x8*>(
            Bs + (wc * 64 + ni * 16 + fr) * 64 + kk * 32 + fq * 8);
#pragma unroll
      for (int mi = 0; mi < 4; ++mi)
#pragma unroll
        for (int ni = 0; ni < 4; ++ni)
          acc[mi][ni] = __builtin_amdgcn_mfma_f32_16x16x32_bf16(
              af[mi], bfr[ni], acc[mi][ni], 0, 0, 0);
    }
    __syncthreads();
  }
  // epilogue: C/D layout col = lane&15, row = (lane>>4)*4 + reg
  const int r0 = fq * 4;
#pragma unroll
  for (int mi = 0; mi < 4; ++mi) {
#pragma unroll
    for (int ni = 0; ni < 4; ++ni) {
      int gr = m0 + wr * 64 + mi * 16 + r0;
      int gc = n0 + wc * 64 + ni * 16 + fr;
#pragma unroll
      for (int r = 0; r < 4; ++r) {
        float val = acc[mi][ni][r];
        size_t off = (size_t)(gr + r) * N + gc;
        if (mode == 0) {
          ((float*)Cout)[off] = val;
        } else if (mode == 2) {
          ((ushort*)Cout)[off] = f2bf(val);
        } else if (mode == 4) {
          ((ushort*)Cout)[off] = f2bf(1.f / (1.f + __expf(-val)));
        } else {
          float u = val + bias[gc];
          ((float*)Cout)[off] = 1.f / (1.f + __expf(u));  // decay = 1 - sigmoid(u)
        }
      }
    }
  }
}

// ---------------- selective scan ----------------
// grid 96 = B*H blocks, 256 threads (4 waves x 16 rows), lane = column j.
// S[i][j]: S = S*decay[i] + k[i]*v[j];  y[j] = sum_i k[i]*S[i][j]
// k, v, r are bf16 in workspace; decay is fp32.
#define LOADSTEP(t, kk, dd, vv)                                     \
  {                                                                 \
    int tc_ = (t) < T_ ? (t) : (T_ - 1);                            \
    const ushort* kp_ = kb + wbase + (size_t)tc_ * D_;              \
    const float* dp_ = dg + wbase + (size_t)tc_ * D_;               \
    bf16x8 k0_ = *reinterpret_cast<const bf16x8*>(kp_);             \
    bf16x8 k1_ = *reinterpret_cast<const bf16x8*>(kp_ + 8);         \
    f32x4 d0_ = *reinterpret_cast<const f32x4*>(dp_);               \
    f32x4 d1_ = *reinterpret_cast<const f32x4*>(dp_ + 4);           \
    f32x4 d2_ = *reinterpret_cast<const f32x4*>(dp_ + 8);           \
    f32x4 d3_ = *reinterpret_cast<const f32x4*>(dp_ + 12);          \
    _Pragma("unroll") for (int p = 0; p < 8; ++p) {                 \
      kk[p] = bf2f((ushort)k0_[p]);                                 \
      kk[p + 8] = bf2f((ushort)k1_[p]);                             \
    }                                                               \
    _Pragma("unroll") for (int p = 0; p < 4; ++p) {                 \
      dd[p] = d0_[p]; dd[p + 4] = d1_[p];                           \
      dd[p + 8] = d2_[p]; dd[p + 12] = d3_[p];                      \
    }                                                               \
    vv = bf2f(vb[base + (size_t)tc_ * D_ + lane]);                  \
  }

#define STEP(kk, dd, vv, tt)                                  \
  {                                                           \
    float pacc = 0.f;                                         \
    _Pragma("unroll") for (int p = 0; p < 16; ++p) {          \
      float m_ = kk[p] * vv;                                  \
      S[p] = __builtin_fmaf(S[p], dd[p], m_);                 \
      pacc = __builtin_fmaf(kk[p], S[p], pacc);               \
    }                                                         \
    py[wv][tt][lane] = pacc;                                  \
  }

__global__ __launch_bounds__(256) void scan_kernel(
    const ushort* __restrict__ kb, const ushort* __restrict__ vb,
    const float* __restrict__ dg, const ushort* __restrict__ rb,
    ushort* __restrict__ yrow) {
  const int bh = blockIdx.x;
  const int b = bh / H_, h = bh % H_;
  const int tid = threadIdx.x;
  const int wv = tid >> 6;
  const int lane = tid & 63;
  const size_t base = ((size_t)b * T_) * D_ + h * HS_;
  const size_t wbase = base + wv * 16;
  __shared__ float py[4][CHUNK][64];
  float S[16];
#pragma unroll
  for (int p = 0; p < 16; ++p) S[p] = 0.f;

  float kA[16], dA[16], vA;
  float kB[16], dB[16], vB;
  LOADSTEP(0, kA, dA, vA);
  LOADSTEP(1, kB, dB, vB);

  for (int tc = 0; tc < T_; tc += CHUNK) {
    for (int tt = 0; tt < CHUNK; tt += 2) {
      int t = tc + tt;
      STEP(kA, dA, vA, tt);
      LOADSTEP(t + 2, kA, dA, vA);
      STEP(kB, dB, vB, tt + 1);
      LOADSTEP(t + 3, kB, dB, vB);
    }
    __syncthreads();
#pragma unroll
    for (int it = 0; it < (CHUNK * 64 / 256); ++it) {
      int idx = it * 256 + tid;
      int tt2 = idx >> 6, j = idx & 63;
      float y = py[0][tt2][j] + py[1][tt2][j] + py[2][tt2][j] + py[3][tt2][j];
      size_t goff = base + (size_t)(tc + tt2) * D_ + j;
      float rr = bf2f(rb[goff]);
      yrow[goff] = f2bf(y * rr);
    }
    __syncthreads();
  }
}

// ---------------- launch ----------------
extern "C" void kernel_launch(void* const* d_in, const int* in_sizes, int n_in,
                              void* d_out, int out_size, void* d_ws, size_t ws_size,
                              hipStream_t stream) {
  const float* x     = (const float*)d_in[0];
  const float* Wx    = (const float*)d_in[1];
  const float* Ww    = (const float*)d_in[2];
  const float* bw    = (const float*)d_in[3];
  const float* Wk    = (const float*)d_in[4];
  const float* Wv    = (const float*)d_in[5];
  const float* Wr    = (const float*)d_in[6];
  const float* Wo    = (const float*)d_in[7];
  const float* gamma = (const float*)d_in[8];
  const float* beta  = (const float*)d_in[9];
  float* out = (float*)d_out;

  // workspace layout (bytes):
  //   xn  [0,          25165824)   bf16 16384x768
  //   wb  [25165824,   32243712)   bf16 6x768x768
  //   xp  [32243712,   57409536)   bf16
  //   kb  [57409536,   82575360)   bf16
  //   vb  [82575360,  107741184)   bf16
  //   rb  [107741184, 132907008)   bf16
  //   yr  [132907008, 158072832)   bf16
  //   df  [158072832, 208404480)   fp32
  const size_t NEED = 208404480ull;
  if (ws_size < NEED) {
    // canary: workspace too small -> clean zero output (absmax ~= max|ref|, no fault)
    zero_out_kernel<<<2048, 256, 0, stream>>>(out, out_size);
    return;
  }

  char* ws = (char*)d_ws;
  ushort* xn = (ushort*)ws;
  ushort* wb = (ushort*)(ws + 25165824);
  ushort* xp = (ushort*)(ws + 32243712);
  ushort* kb = (ushort*)(ws + 57409536);
  ushort* vb = (ushort*)(ws + 82575360);
  ushort* rb = (ushort*)(ws + 107741184);
  ushort* yr = (ushort*)(ws + 132907008);
  float*  df = (float*)(ws + 158072832);

  ushort* WxB = wb;
  ushort* WwB = wb + 1 * 589824;
  ushort* WkB = wb + 2 * 589824;
  ushort* WvB = wb + 3 * 589824;
  ushort* WrB = wb + 4 * 589824;
  ushort* WoB = wb + 5 * 589824;

  cast_w_kernel<<<576, 256, 0, stream>>>(Wx, WxB);
  cast_w_kernel<<<576, 256, 0, stream>>>(Ww, WwB);
  cast_w_kernel<<<576, 256, 0, stream>>>(Wk, WkB);
  cast_w_kernel<<<576, 256, 0, stream>>>(Wv, WvB);
  cast_w_kernel<<<576, 256, 0, stream>>>(Wr, WrB);
  cast_w_kernel<<<576, 256, 0, stream>>>(Wo, WoB);
  ln_kernel<<<4096, 256, 0, stream>>>(x, gamma, beta, xn);

  gemm_bt<<<dim3(128, 6), 256, 0, stream>>>(xn, WkB, kb, nullptr, 2);   // k  (bf16)
  gemm_bt<<<dim3(128, 6), 256, 0, stream>>>(xn, WvB, vb, nullptr, 2);   // v  (bf16)
  gemm_bt<<<dim3(128, 6), 256, 0, stream>>>(xn, WrB, rb, nullptr, 4);   // r  (bf16 sigmoid)
  gemm_bt<<<dim3(128, 6), 256, 0, stream>>>(xn, WxB, xp, nullptr, 2);   // xp (bf16)
  gemm_bt<<<dim3(128, 6), 256, 0, stream>>>(xp, WwB, df, bw, 3);        // decay (fp32)

  scan_kernel<<<96, 256, 0, stream>>>(kb, vb, df, rb, yr);

  gemm_bt<<<dim3(128, 6), 256, 0, stream>>>(yr, WoB, out, nullptr, 0);  // final (fp32)
}

// Round 4
// 674.214 us; speedup vs baseline: 1.5592x; 1.5592x over previous
//
#include <hip/hip_runtime.h>

#define B_ 8
#define T_ 2048
#define D_ 768
#define H_ 12
#define HS_ 64
#define LN_EPS 1e-5f
#define NC 16    // chunks
#define TC 128   // timesteps per chunk
#define CHUNK 32 // LDS y-reduce granularity

typedef __attribute__((ext_vector_type(8))) short bf16x8;
typedef __attribute__((ext_vector_type(4))) float f32x4;

__device__ __forceinline__ ushort f2bf(float f) {
  unsigned u = __builtin_bit_cast(unsigned, f);
  unsigned r = (u + 0x7FFFu + ((u >> 16) & 1u)) >> 16;
  return (ushort)r;
}
__device__ __forceinline__ float bf2f(ushort u) {
  return __builtin_bit_cast(float, ((unsigned)u) << 16);
}

// ---------------- canary ----------------
__global__ __launch_bounds__(256) void zero_out_kernel(float* __restrict__ out, int n) {
  for (int i = blockIdx.x * 256 + threadIdx.x; i < n; i += gridDim.x * 256)
    out[i] = 0.f;
}

// ---------------- weight cast ----------------
__global__ __launch_bounds__(256) void cast_w_kernel(
    const float* __restrict__ src, ushort* __restrict__ dst) {
  int idx = (blockIdx.x * 256 + threadIdx.x) * 4;
  float4 v = *reinterpret_cast<const float4*>(src + idx);
  ushort4 o;
  o.x = f2bf(v.x); o.y = f2bf(v.y); o.z = f2bf(v.z); o.w = f2bf(v.w);
  *reinterpret_cast<ushort4*>(dst + idx) = o;
}

// ---------------- LayerNorm ----------------
__global__ __launch_bounds__(256) void ln_kernel(
    const float* __restrict__ x, const float* __restrict__ gamma,
    const float* __restrict__ beta, ushort* __restrict__ xn) {
  const int wv = threadIdx.x >> 6;
  const int lane = threadIdx.x & 63;
  const int row = blockIdx.x * 4 + wv;
  const float* xr = x + (size_t)row * D_;
  float4 a[3];
#pragma unroll
  for (int s = 0; s < 3; ++s)
    a[s] = *reinterpret_cast<const float4*>(xr + s * 256 + lane * 4);
  float sum = 0.f;
#pragma unroll
  for (int s = 0; s < 3; ++s) sum += a[s].x + a[s].y + a[s].z + a[s].w;
#pragma unroll
  for (int off = 32; off; off >>= 1) sum += __shfl_xor(sum, off);
  float mu = sum * (1.f / 768.f);
  float vs = 0.f;
#pragma unroll
  for (int s = 0; s < 3; ++s) {
    float dx = a[s].x - mu, dy = a[s].y - mu, dz = a[s].z - mu, dw = a[s].w - mu;
    vs += dx * dx + dy * dy + dz * dz + dw * dw;
  }
#pragma unroll
  for (int off = 32; off; off >>= 1) vs += __shfl_xor(vs, off);
  float rs = rsqrtf(vs * (1.f / 768.f) + LN_EPS);
  ushort* orow = xn + (size_t)row * D_;
#pragma unroll
  for (int s = 0; s < 3; ++s) {
    int col = s * 256 + lane * 4;
    float4 g = *reinterpret_cast<const float4*>(gamma + col);
    float4 bb = *reinterpret_cast<const float4*>(beta + col);
    ushort4 o;
    o.x = f2bf((a[s].x - mu) * rs * g.x + bb.x);
    o.y = f2bf((a[s].y - mu) * rs * g.y + bb.y);
    o.z = f2bf((a[s].z - mu) * rs * g.z + bb.z);
    o.w = f2bf((a[s].w - mu) * rs * g.w + bb.w);
    *reinterpret_cast<ushort4*>(orow + col) = o;
  }
}

// ---------------- bf16 MFMA GEMM (global_load_lds staging) ----------------
// C[m,n] = sum_k A[m,k]*W[n,k].  M=16384, N=768, K=768.
// modes: 0 fp32 plain, 2 bf16 plain, 3 fp32 decay=1-sigmoid(val+bias), 4 bf16 sigmoid
__global__ __launch_bounds__(256) void gemm_bt(
    const ushort* __restrict__ A, const ushort* __restrict__ W,
    void* __restrict__ Cout, const float* __restrict__ bias, int mode) {
  constexpr int K = 768, N = 768;
  __shared__ __align__(16) ushort As[128 * 64];
  __shared__ __align__(16) ushort Bs[128 * 64];
  const int tid = threadIdx.x;
  const int wv = tid >> 6, lane = tid & 63;
  const int m0 = blockIdx.x * 128, n0 = blockIdx.y * 128;
  const int wr = wv >> 1, wc = wv & 1;
  const int lrow = lane >> 3, lcol = (lane & 7) * 8;
  const int fr = lane & 15, fq = lane >> 4;
  f32x4 zero = {0.f, 0.f, 0.f, 0.f};
  f32x4 acc[4][4];
#pragma unroll
  for (int mi = 0; mi < 4; ++mi)
#pragma unroll
    for (int ni = 0; ni < 4; ++ni) acc[mi][ni] = zero;

  for (int k0 = 0; k0 < K; k0 += 64) {
#pragma unroll
    for (int it = 0; it < 4; ++it) {
      int chunk = it * 4 + wv;
      int row = chunk * 8 + lrow;
      const ushort* gA = A + (size_t)(m0 + row) * K + k0 + lcol;
      const ushort* gB = W + (size_t)(n0 + row) * K + k0 + lcol;
      __builtin_amdgcn_global_load_lds(
          (const __attribute__((address_space(1))) void*)gA,
          (__attribute__((address_space(3))) void*)(As + chunk * 512), 16, 0, 0);
      __builtin_amdgcn_global_load_lds(
          (const __attribute__((address_space(1))) void*)gB,
          (__attribute__((address_space(3))) void*)(Bs + chunk * 512), 16, 0, 0);
    }
    __syncthreads();
#pragma unroll
    for (int kk = 0; kk < 2; ++kk) {
      bf16x8 af[4], bfr[4];
#pragma unroll
      for (int mi = 0; mi < 4; ++mi)
        af[mi] = *reinterpret_cast<const bf16x8*>(
            As + (wr * 64 + mi * 16 + fr) * 64 + kk * 32 + fq * 8);
#pragma unroll
      for (int ni = 0; ni < 4; ++ni)
        bfr[ni] = *reinterpret_cast<const bf16x8*>(
            Bs + (wc * 64 + ni * 16 + fr) * 64 + kk * 32 + fq * 8);
#pragma unroll
      for (int mi = 0; mi < 4; ++mi)
#pragma unroll
        for (int ni = 0; ni < 4; ++ni)
          acc[mi][ni] = __builtin_amdgcn_mfma_f32_16x16x32_bf16(
              af[mi], bfr[ni], acc[mi][ni], 0, 0, 0);
    }
    __syncthreads();
  }
  const int r0 = fq * 4;
#pragma unroll
  for (int mi = 0; mi < 4; ++mi) {
#pragma unroll
    for (int ni = 0; ni < 4; ++ni) {
      int gr = m0 + wr * 64 + mi * 16 + r0;
      int gc = n0 + wc * 64 + ni * 16 + fr;
#pragma unroll
      for (int r = 0; r < 4; ++r) {
        float val = acc[mi][ni][r];
        size_t off = (size_t)(gr + r) * N + gc;
        if (mode == 0) {
          ((float*)Cout)[off] = val;
        } else if (mode == 2) {
          ((ushort*)Cout)[off] = f2bf(val);
        } else if (mode == 4) {
          ((ushort*)Cout)[off] = f2bf(1.f / (1.f + __expf(-val)));
        } else {
          float u = val + bias[gc];
          ((float*)Cout)[off] = 1.f / (1.f + __expf(u));  // decay = 1 - sigmoid
        }
      }
    }
  }
}

// ---------------- chunked selective scan ----------------
// S[i][j]_t = d_t[i]*S_{t-1} + k_t[i]*v_t[j];  y_t[j] = sum_i k_t[i]*S[i][j]_t
// Linear per-(i,j) recurrence -> 3-pass chunked scan over NC chunks of TC steps.
#define LOADSTEP(t, kk, dd, vv)                                     \
  {                                                                 \
    int tc_ = (t) < T_ ? (t) : (T_ - 1);                            \
    const ushort* kp_ = kb + wbase + (size_t)tc_ * D_;              \
    const float* dp_ = dg + wbase + (size_t)tc_ * D_;               \
    bf16x8 k0_ = *reinterpret_cast<const bf16x8*>(kp_);             \
    bf16x8 k1_ = *reinterpret_cast<const bf16x8*>(kp_ + 8);         \
    f32x4 d0_ = *reinterpret_cast<const f32x4*>(dp_);               \
    f32x4 d1_ = *reinterpret_cast<const f32x4*>(dp_ + 4);           \
    f32x4 d2_ = *reinterpret_cast<const f32x4*>(dp_ + 8);           \
    f32x4 d3_ = *reinterpret_cast<const f32x4*>(dp_ + 12);          \
    _Pragma("unroll") for (int p = 0; p < 8; ++p) {                 \
      kk[p] = bf2f((ushort)k0_[p]);                                 \
      kk[p + 8] = bf2f((ushort)k1_[p]);                             \
    }                                                               \
    _Pragma("unroll") for (int p = 0; p < 4; ++p) {                 \
      dd[p] = d0_[p]; dd[p + 4] = d1_[p];                           \
      dd[p + 8] = d2_[p]; dd[p + 12] = d3_[p];                      \
    }                                                               \
    vv = bf2f(vb[base + (size_t)tc_ * D_ + lane]);                  \
  }

// pass 1: local scan from zero; emit final local state + decay products
__global__ __launch_bounds__(256) void scan_local(
    const ushort* __restrict__ kb, const ushort* __restrict__ vb,
    const float* __restrict__ dg, float* __restrict__ SL,
    float* __restrict__ Pd) {
  const int bh = blockIdx.x, c = blockIdx.y;
  const int tid = threadIdx.x;
  const int wv = tid >> 6, lane = tid & 63;
  const size_t base = ((size_t)(bh / H_) * T_) * D_ + (bh % H_) * HS_;
  const size_t wbase = base + wv * 16;
  float S[16], Dc[16];
#pragma unroll
  for (int p = 0; p < 16; ++p) { S[p] = 0.f; Dc[p] = 1.f; }

  float kA[16], dA[16], vA;
  float kB[16], dB[16], vB;
  const int t0 = c * TC;
  LOADSTEP(t0 + 0, kA, dA, vA);
  LOADSTEP(t0 + 1, kB, dB, vB);
  for (int tt = 0; tt < TC; tt += 2) {
    int t = t0 + tt;
#pragma unroll
    for (int p = 0; p < 16; ++p) {
      S[p] = __builtin_fmaf(S[p], dA[p], kA[p] * vA);
      Dc[p] *= dA[p];
    }
    LOADSTEP(t + 2, kA, dA, vA);
#pragma unroll
    for (int p = 0; p < 16; ++p) {
      S[p] = __builtin_fmaf(S[p], dB[p], kB[p] * vB);
      Dc[p] *= dB[p];
    }
    LOADSTEP(t + 3, kB, dB, vB);
  }
  float* sl = SL + ((size_t)bh * NC + c) * 4096;
#pragma unroll
  for (int p = 0; p < 16; ++p) sl[(wv * 16 + p) * 64 + lane] = S[p];
  float* pp = Pd + ((size_t)bh * NC + c) * 64 + wv * 16;
#pragma unroll
  for (int p = 0; p < 16; ++p)
    if (lane == 0) pp[p] = Dc[p];
}

// pass 2: per-(i,j) chain over chunks; convert local-final -> chunk-initial (in place)
__global__ __launch_bounds__(256) void scan_chain(
    float* __restrict__ SL, const float* __restrict__ Pd) {
  const int bh = blockIdx.x;
  const int e = blockIdx.y * 256 + threadIdx.x;  // element in [0,4096)
  const int i = e >> 6;
  float sinit = 0.f;
#pragma unroll
  for (int c = 0; c < NC; ++c) {
    size_t mo = ((size_t)bh * NC + c) * 4096 + e;
    float L = SL[mo];
    float P = Pd[((size_t)bh * NC + c) * 64 + i];
    SL[mo] = sinit;
    sinit = __builtin_fmaf(P, sinit, L);
  }
}

// pass 3: re-scan each chunk from its true initial state; emit y*r (bf16)
__global__ __launch_bounds__(256) void scan_apply(
    const ushort* __restrict__ kb, const ushort* __restrict__ vb,
    const float* __restrict__ dg, const ushort* __restrict__ rb,
    const float* __restrict__ SL, ushort* __restrict__ yrow) {
  const int bh = blockIdx.x, c = blockIdx.y;
  const int tid = threadIdx.x;
  const int wv = tid >> 6, lane = tid & 63;
  const size_t base = ((size_t)(bh / H_) * T_) * D_ + (bh % H_) * HS_;
  const size_t wbase = base + wv * 16;
  __shared__ float py[4][CHUNK][64];
  float S[16];
  const float* sl = SL + ((size_t)bh * NC + c) * 4096;
#pragma unroll
  for (int p = 0; p < 16; ++p) S[p] = sl[(wv * 16 + p) * 64 + lane];

  float kA[16], dA[16], vA;
  float kB[16], dB[16], vB;
  const int t0 = c * TC;
  LOADSTEP(t0 + 0, kA, dA, vA);
  LOADSTEP(t0 + 1, kB, dB, vB);

  for (int tc = t0; tc < t0 + TC; tc += CHUNK) {
    for (int tt = 0; tt < CHUNK; tt += 2) {
      int t = tc + tt;
      {
        float pacc = 0.f;
#pragma unroll
        for (int p = 0; p < 16; ++p) {
          S[p] = __builtin_fmaf(S[p], dA[p], kA[p] * vA);
          pacc = __builtin_fmaf(kA[p], S[p], pacc);
        }
        py[wv][tt][lane] = pacc;
      }
      LOADSTEP(t + 2, kA, dA, vA);
      {
        float pacc = 0.f;
#pragma unroll
        for (int p = 0; p < 16; ++p) {
          S[p] = __builtin_fmaf(S[p], dB[p], kB[p] * vB);
          pacc = __builtin_fmaf(kB[p], S[p], pacc);
        }
        py[wv][tt + 1][lane] = pacc;
      }
      LOADSTEP(t + 3, kB, dB, vB);
    }
    __syncthreads();
#pragma unroll
    for (int it = 0; it < (CHUNK * 64 / 256); ++it) {
      int idx = it * 256 + tid;
      int tt2 = idx >> 6, j = idx & 63;
      float y = py[0][tt2][j] + py[1][tt2][j] + py[2][tt2][j] + py[3][tt2][j];
      size_t goff = base + (size_t)(tc + tt2) * D_ + j;
      float rr = bf2f(rb[goff]);
      yrow[goff] = f2bf(y * rr);
    }
    __syncthreads();
  }
}

// ---------------- launch ----------------
extern "C" void kernel_launch(void* const* d_in, const int* in_sizes, int n_in,
                              void* d_out, int out_size, void* d_ws, size_t ws_size,
                              hipStream_t stream) {
  const float* x     = (const float*)d_in[0];
  const float* Wx    = (const float*)d_in[1];
  const float* Ww    = (const float*)d_in[2];
  const float* bw    = (const float*)d_in[3];
  const float* Wk    = (const float*)d_in[4];
  const float* Wv    = (const float*)d_in[5];
  const float* Wr    = (const float*)d_in[6];
  const float* Wo    = (const float*)d_in[7];
  const float* gamma = (const float*)d_in[8];
  const float* beta  = (const float*)d_in[9];
  float* out = (float*)d_out;

  // workspace layout (bytes):
  //   xn  [0,          25165824)   bf16 16384x768   (reused as SL by scan: fp32 96*16*4096)
  //   wb  [25165824,   32243712)   bf16 6x768x768
  //   xp  [32243712,   57409536)   bf16             (reused: Pd fp32 96*16*64 at start)
  //   kb  [57409536,   82575360)   bf16
  //   vb  [82575360,  107741184)   bf16
  //   rb  [107741184, 132907008)   bf16
  //   yr  [132907008, 158072832)   bf16
  //   df  [158072832, 208404480)   fp32
  const size_t NEED = 208404480ull;
  if (ws_size < NEED) {
    zero_out_kernel<<<2048, 256, 0, stream>>>(out, out_size);
    return;
  }

  char* ws = (char*)d_ws;
  ushort* xn = (ushort*)ws;
  ushort* wb = (ushort*)(ws + 25165824);
  ushort* xp = (ushort*)(ws + 32243712);
  ushort* kb = (ushort*)(ws + 57409536);
  ushort* vb = (ushort*)(ws + 82575360);
  ushort* rb = (ushort*)(ws + 107741184);
  ushort* yr = (ushort*)(ws + 132907008);
  float*  df = (float*)(ws + 158072832);
  float*  SL = (float*)ws;               // aliases xn (dead before scan)
  float*  Pd = (float*)(ws + 32243712);  // aliases xp (dead before scan)

  ushort* WxB = wb;
  ushort* WwB = wb + 1 * 589824;
  ushort* WkB = wb + 2 * 589824;
  ushort* WvB = wb + 3 * 589824;
  ushort* WrB = wb + 4 * 589824;
  ushort* WoB = wb + 5 * 589824;

  cast_w_kernel<<<576, 256, 0, stream>>>(Wx, WxB);
  cast_w_kernel<<<576, 256, 0, stream>>>(Ww, WwB);
  cast_w_kernel<<<576, 256, 0, stream>>>(Wk, WkB);
  cast_w_kernel<<<576, 256, 0, stream>>>(Wv, WvB);
  cast_w_kernel<<<576, 256, 0, stream>>>(Wr, WrB);
  cast_w_kernel<<<576, 256, 0, stream>>>(Wo, WoB);
  ln_kernel<<<4096, 256, 0, stream>>>(x, gamma, beta, xn);

  gemm_bt<<<dim3(128, 6), 256, 0, stream>>>(xn, WkB, kb, nullptr, 2);   // k  (bf16)
  gemm_bt<<<dim3(128, 6), 256, 0, stream>>>(xn, WvB, vb, nullptr, 2);   // v  (bf16)
  gemm_bt<<<dim3(128, 6), 256, 0, stream>>>(xn, WrB, rb, nullptr, 4);   // r  (bf16 sigmoid)
  gemm_bt<<<dim3(128, 6), 256, 0, stream>>>(xn, WxB, xp, nullptr, 2);   // xp (bf16)
  gemm_bt<<<dim3(128, 6), 256, 0, stream>>>(xp, WwB, df, bw, 3);        // decay (fp32)

  scan_local<<<dim3(96, NC), 256, 0, stream>>>(kb, vb, df, SL, Pd);
  scan_chain<<<dim3(96, 16), 256, 0, stream>>>(SL, Pd);
  scan_apply<<<dim3(96, NC), 256, 0, stream>>>(kb, vb, df, rb, SL, yr);

  gemm_bt<<<dim3(128, 6), 256, 0, stream>>>(yr, WoB, out, nullptr, 0);  // final (fp32)
}

// Round 5
// 359.144 us; speedup vs baseline: 2.9270x; 1.8773x over previous
//
#include <hip/hip_runtime.h>

#define B_ 8
#define T_ 2048
#define D_ 768
#define H_ 12
#define HS_ 64
#define LN_EPS 1e-5f
#define NC 32   // chunks
#define TC 64   // timesteps per chunk
#define PA 72   // LDS pitch (halves) for row-read tiles (144B, 16B-aligned)
#define PV 68   // LDS pitch (halves) for transposed-read tiles (136B, 2-way max)

typedef __attribute__((ext_vector_type(8))) short bf16x8;
typedef __attribute__((ext_vector_type(4))) float f32x4;

__device__ __forceinline__ ushort f2bf(float f) {
  unsigned u = __builtin_bit_cast(unsigned, f);
  unsigned r = (u + 0x7FFFu + ((u >> 16) & 1u)) >> 16;
  return (ushort)r;
}
__device__ __forceinline__ float bf2f(ushort u) {
  return __builtin_bit_cast(float, ((unsigned)u) << 16);
}

// transposed fragment read: elem e = tile[(r0+e)*PV + col]
__device__ __forceinline__ bf16x8 ldsT68(const ushort* tile, int r0, int col) {
  bf16x8 r;
#pragma unroll
  for (int e = 0; e < 8; ++e) r[e] = (short)tile[(r0 + e) * PV + col];
  return r;
}

// ---------------- canary ----------------
__global__ __launch_bounds__(256) void zero_out_kernel(float* __restrict__ out, int n) {
  for (int i = blockIdx.x * 256 + threadIdx.x; i < n; i += gridDim.x * 256)
    out[i] = 0.f;
}

// ---------------- weight cast ----------------
__global__ __launch_bounds__(256) void cast_w_kernel(
    const float* __restrict__ src, ushort* __restrict__ dst) {
  int idx = (blockIdx.x * 256 + threadIdx.x) * 4;
  float4 v = *reinterpret_cast<const float4*>(src + idx);
  ushort4 o;
  o.x = f2bf(v.x); o.y = f2bf(v.y); o.z = f2bf(v.z); o.w = f2bf(v.w);
  *reinterpret_cast<ushort4*>(dst + idx) = o;
}

// ---------------- LayerNorm ----------------
__global__ __launch_bounds__(256) void ln_kernel(
    const float* __restrict__ x, const float* __restrict__ gamma,
    const float* __restrict__ beta, ushort* __restrict__ xn) {
  const int wv = threadIdx.x >> 6;
  const int lane = threadIdx.x & 63;
  const int row = blockIdx.x * 4 + wv;
  const float* xr = x + (size_t)row * D_;
  float4 a[3];
#pragma unroll
  for (int s = 0; s < 3; ++s)
    a[s] = *reinterpret_cast<const float4*>(xr + s * 256 + lane * 4);
  float sum = 0.f;
#pragma unroll
  for (int s = 0; s < 3; ++s) sum += a[s].x + a[s].y + a[s].z + a[s].w;
#pragma unroll
  for (int off = 32; off; off >>= 1) sum += __shfl_xor(sum, off);
  float mu = sum * (1.f / 768.f);
  float vs = 0.f;
#pragma unroll
  for (int s = 0; s < 3; ++s) {
    float dx = a[s].x - mu, dy = a[s].y - mu, dz = a[s].z - mu, dw = a[s].w - mu;
    vs += dx * dx + dy * dy + dz * dz + dw * dw;
  }
#pragma unroll
  for (int off = 32; off; off >>= 1) vs += __shfl_xor(vs, off);
  float rs = rsqrtf(vs * (1.f / 768.f) + LN_EPS);
  ushort* orow = xn + (size_t)row * D_;
#pragma unroll
  for (int s = 0; s < 3; ++s) {
    int col = s * 256 + lane * 4;
    float4 g = *reinterpret_cast<const float4*>(gamma + col);
    float4 bb = *reinterpret_cast<const float4*>(beta + col);
    ushort4 o;
    o.x = f2bf((a[s].x - mu) * rs * g.x + bb.x);
    o.y = f2bf((a[s].y - mu) * rs * g.y + bb.y);
    o.z = f2bf((a[s].z - mu) * rs * g.z + bb.z);
    o.w = f2bf((a[s].w - mu) * rs * g.w + bb.w);
    *reinterpret_cast<ushort4*>(orow + col) = o;
  }
}

// ---------------- bf16 MFMA GEMM (single output) ----------------
// C[m,n] = sum_k A[m,k]*W[n,k].  M=16384, N=768, K=768.
// modes: 0 fp32 plain, 3 fp32 decay=1-sigmoid(val+bias)
__global__ __launch_bounds__(256) void gemm_bt(
    const ushort* __restrict__ A, const ushort* __restrict__ W,
    void* __restrict__ Cout, const float* __restrict__ bias, int mode) {
  constexpr int K = 768, N = 768;
  __shared__ __align__(16) ushort As[128 * 64];
  __shared__ __align__(16) ushort Bs[128 * 64];
  const int tid = threadIdx.x;
  const int wv = tid >> 6, lane = tid & 63;
  const int m0 = blockIdx.x * 128, n0 = blockIdx.y * 128;
  const int wr = wv >> 1, wc = wv & 1;
  const int lrow = lane >> 3, lcol = (lane & 7) * 8;
  const int fr = lane & 15, fq = lane >> 4;
  f32x4 zero = {0.f, 0.f, 0.f, 0.f};
  f32x4 acc[4][4];
#pragma unroll
  for (int mi = 0; mi < 4; ++mi)
#pragma unroll
    for (int ni = 0; ni < 4; ++ni) acc[mi][ni] = zero;

  for (int k0 = 0; k0 < K; k0 += 64) {
#pragma unroll
    for (int it = 0; it < 4; ++it) {
      int chunk = it * 4 + wv;
      int row = chunk * 8 + lrow;
      const ushort* gA = A + (size_t)(m0 + row) * K + k0 + lcol;
      const ushort* gB = W + (size_t)(n0 + row) * K + k0 + lcol;
      __builtin_amdgcn_global_load_lds(
          (const __attribute__((address_space(1))) void*)gA,
          (__attribute__((address_space(3))) void*)(As + chunk * 512), 16, 0, 0);
      __builtin_amdgcn_global_load_lds(
          (const __attribute__((address_space(1))) void*)gB,
          (__attribute__((address_space(3))) void*)(Bs + chunk * 512), 16, 0, 0);
    }
    __syncthreads();
#pragma unroll
    for (int kk = 0; kk < 2; ++kk) {
      bf16x8 af[4], bfr[4];
#pragma unroll
      for (int mi = 0; mi < 4; ++mi)
        af[mi] = *reinterpret_cast<const bf16x8*>(
            As + (wr * 64 + mi * 16 + fr) * 64 + kk * 32 + fq * 8);
#pragma unroll
      for (int ni = 0; ni < 4; ++ni)
        bfr[ni] = *reinterpret_cast<const bf16x8*>(
            Bs + (wc * 64 + ni * 16 + fr) * 64 + kk * 32 + fq * 8);
#pragma unroll
      for (int mi = 0; mi < 4; ++mi)
#pragma unroll
        for (int ni = 0; ni < 4; ++ni)
          acc[mi][ni] = __builtin_amdgcn_mfma_f32_16x16x32_bf16(
              af[mi], bfr[ni], acc[mi][ni], 0, 0, 0);
    }
    __syncthreads();
  }
  const int r0 = fq * 4;
#pragma unroll
  for (int mi = 0; mi < 4; ++mi) {
#pragma unroll
    for (int ni = 0; ni < 4; ++ni) {
      int gr = m0 + wr * 64 + mi * 16 + r0;
      int gc = n0 + wc * 64 + ni * 16 + fr;
#pragma unroll
      for (int r = 0; r < 4; ++r) {
        float val = acc[mi][ni][r];
        size_t off = (size_t)(gr + r) * N + gc;
        if (mode == 0) {
          ((float*)Cout)[off] = val;
        } else {
          float u = val + bias[gc];
          ((float*)Cout)[off] = 1.f / (1.f + __expf(u));  // decay = 1 - sigmoid
        }
      }
    }
  }
}

// ---------------- fused k/v/r/xp GEMM: N=3072 concatenated weights ----------------
__global__ __launch_bounds__(256) void gemm_cat(
    const ushort* __restrict__ A, const ushort* __restrict__ Wcat,
    ushort* __restrict__ kb, ushort* __restrict__ vb,
    ushort* __restrict__ rb, ushort* __restrict__ xp) {
  constexpr int K = 768;
  __shared__ __align__(16) ushort As[128 * 64];
  __shared__ __align__(16) ushort Bs[128 * 64];
  const int tid = threadIdx.x;
  const int wv = tid >> 6, lane = tid & 63;
  const int m0 = blockIdx.x * 128, n0 = blockIdx.y * 128;
  const int wr = wv >> 1, wc = wv & 1;
  const int lrow = lane >> 3, lcol = (lane & 7) * 8;
  const int fr = lane & 15, fq = lane >> 4;
  f32x4 zero = {0.f, 0.f, 0.f, 0.f};
  f32x4 acc[4][4];
#pragma unroll
  for (int mi = 0; mi < 4; ++mi)
#pragma unroll
    for (int ni = 0; ni < 4; ++ni) acc[mi][ni] = zero;

  for (int k0 = 0; k0 < K; k0 += 64) {
#pragma unroll
    for (int it = 0; it < 4; ++it) {
      int chunk = it * 4 + wv;
      int row = chunk * 8 + lrow;
      const ushort* gA = A + (size_t)(m0 + row) * K + k0 + lcol;
      const ushort* gB = Wcat + (size_t)(n0 + row) * K + k0 + lcol;
      __builtin_amdgcn_global_load_lds(
          (const __attribute__((address_space(1))) void*)gA,
          (__attribute__((address_space(3))) void*)(As + chunk * 512), 16, 0, 0);
      __builtin_amdgcn_global_load_lds(
          (const __attribute__((address_space(1))) void*)gB,
          (__attribute__((address_space(3))) void*)(Bs + chunk * 512), 16, 0, 0);
    }
    __syncthreads();
#pragma unroll
    for (int kk = 0; kk < 2; ++kk) {
      bf16x8 af[4], bfr[4];
#pragma unroll
      for (int mi = 0; mi < 4; ++mi)
        af[mi] = *reinterpret_cast<const bf16x8*>(
            As + (wr * 64 + mi * 16 + fr) * 64 + kk * 32 + fq * 8);
#pragma unroll
      for (int ni = 0; ni < 4; ++ni)
        bfr[ni] = *reinterpret_cast<const bf16x8*>(
            Bs + (wc * 64 + ni * 16 + fr) * 64 + kk * 32 + fq * 8);
#pragma unroll
      for (int mi = 0; mi < 4; ++mi)
#pragma unroll
        for (int ni = 0; ni < 4; ++ni)
          acc[mi][ni] = __builtin_amdgcn_mfma_f32_16x16x32_bf16(
              af[mi], bfr[ni], acc[mi][ni], 0, 0, 0);
    }
    __syncthreads();
  }
  // 128-wide blocks never straddle a 768 boundary (768 = 6*128)
  const int sel = n0 / 768;
  const int nbase = n0 - sel * 768;
  ushort* dst = sel == 0 ? kb : sel == 1 ? vb : sel == 2 ? rb : xp;
  const bool sig = (sel == 2);
  const int r0 = fq * 4;
#pragma unroll
  for (int mi = 0; mi < 4; ++mi) {
#pragma unroll
    for (int ni = 0; ni < 4; ++ni) {
      int gr = m0 + wr * 64 + mi * 16 + r0;
      int gc = nbase + wc * 64 + ni * 16 + fr;
#pragma unroll
      for (int r = 0; r < 4; ++r) {
        float val = acc[mi][ni][r];
        if (sig) val = 1.f / (1.f + __expf(-val));
        dst[(size_t)(gr + r) * 768 + gc] = f2bf(val);
      }
    }
  }
}

// ---------------- scan prep: cumulative decay products per chunk ----------------
// a_t[i] = prod_{u=t0..t} d_u[i];  kA = k*a (bf16), kIA = k/a (bf16), aend fp32
__global__ __launch_bounds__(64) void scan_prep(
    const ushort* __restrict__ kb, const float* __restrict__ dg,
    ushort* __restrict__ kA, ushort* __restrict__ kIA, float* __restrict__ aend) {
  const int bh = blockIdx.x, c = blockIdx.y;
  const int b = bh / H_, h = bh % H_;
  const int i = threadIdx.x;  // 0..63
  size_t go = (size_t)b * T_ * D_ + (size_t)(c * TC) * D_ + h * HS_ + i;
  size_t co = ((size_t)bh * T_ + (size_t)c * TC) * HS_ + i;
  float a = 1.f;
#pragma unroll 4
  for (int t = 0; t < TC; ++t) {
    float d = dg[go];
    float k = bf2f(kb[go]);
    a *= d;
    kA[co] = f2bf(k * a);
    kIA[co] = f2bf(k / a);
    go += D_;
    co += HS_;
  }
  aend[((size_t)bh * NC + c) * HS_ + i] = a;
}

// ---------------- scan Mc: Mc[i][j] = sum_s kIA[s][i] * V[s][j] ----------------
__global__ __launch_bounds__(256) void scan_mc(
    const ushort* __restrict__ kIA, const ushort* __restrict__ vb,
    char* __restrict__ McBase) {
  __shared__ __align__(16) ushort kt[TC * PV];
  __shared__ __align__(16) ushort vt[TC * PV];
  const int bh = blockIdx.x, c = blockIdx.y;
  const int b = bh / H_, h = bh % H_;
  const int tid = threadIdx.x;
  const int w = tid >> 6, lane = tid & 63;
  const int fr = lane & 15, fq = lane >> 4;
  {
    const int row = tid >> 2, col = (tid & 3) * 16;
    const ushort* gki = kIA + ((size_t)bh * T_ + (size_t)c * TC + row) * HS_ + col;
    const ushort* gv = vb + ((size_t)b * T_ + (size_t)c * TC + row) * D_ + h * HS_ + col;
    uint4 i0 = *(const uint4*)gki; uint4 i1 = *(const uint4*)(gki + 8);
    uint4 v0 = *(const uint4*)gv;  uint4 v1 = *(const uint4*)(gv + 8);
    ushort* pk = kt + row * PV + col;
    *(uint2*)(pk + 0) = make_uint2(i0.x, i0.y);
    *(uint2*)(pk + 4) = make_uint2(i0.z, i0.w);
    *(uint2*)(pk + 8) = make_uint2(i1.x, i1.y);
    *(uint2*)(pk + 12) = make_uint2(i1.z, i1.w);
    ushort* pv = vt + row * PV + col;
    *(uint2*)(pv + 0) = make_uint2(v0.x, v0.y);
    *(uint2*)(pv + 4) = make_uint2(v0.z, v0.w);
    *(uint2*)(pv + 8) = make_uint2(v1.x, v1.y);
    *(uint2*)(pv + 12) = make_uint2(v1.z, v1.w);
  }
  __syncthreads();
  f32x4 zero = {0.f, 0.f, 0.f, 0.f};
  f32x4 acc[4] = {zero, zero, zero, zero};
#pragma unroll
  for (int kk = 0; kk < 2; ++kk) {
    bf16x8 af = ldsT68(kt, kk * 32 + fq * 8, w * 16 + fr);  // A[m=i][k=s]
#pragma unroll
    for (int nf = 0; nf < 4; ++nf) {
      bf16x8 b8 = ldsT68(vt, kk * 32 + fq * 8, nf * 16 + fr);  // B[n=j][k=s]
      acc[nf] = __builtin_amdgcn_mfma_f32_16x16x32_bf16(af, b8, acc[nf], 0, 0, 0);
    }
  }
  float* mc = (float*)(McBase + ((size_t)bh * NC + c) * 16384);
#pragma unroll
  for (int nf = 0; nf < 4; ++nf)
#pragma unroll
    for (int rr = 0; rr < 4; ++rr) {
      int i = w * 16 + fq * 4 + rr, j = nf * 16 + fr;
      mc[i * 64 + j] = acc[nf][rr];
    }
}

// ---------------- scan chain: S0_{c+1} = aend_c (+) (S0_c + Mc_c); emit S0 bf16 ----------------
// S0 bf16 [i][j] overlaid on the first 8KB of each 16KB Mc slot.
__global__ __launch_bounds__(256) void scan_chain(
    char* __restrict__ McBase, const float* __restrict__ aend) {
  const int bh = blockIdx.x;
  const int i = threadIdx.x >> 2, j0 = (threadIdx.x & 3) * 16;
  float S[16];
#pragma unroll
  for (int p = 0; p < 16; ++p) S[p] = 0.f;
  for (int c = 0; c < NC; ++c) {
    char* slot = McBase + ((size_t)bh * NC + c) * 16384;
    const float* mc = (const float*)slot + i * 64 + j0;
    float m[16];
#pragma unroll
    for (int p = 0; p < 16; ++p) m[p] = mc[p];
    __syncthreads();  // all Mc reads before overlay writes
    ushort* s0 = (ushort*)slot + i * 64 + j0;
#pragma unroll
    for (int p = 0; p < 16; ++p) s0[p] = f2bf(S[p]);
    float ae = aend[((size_t)bh * NC + c) * HS_ + i];
#pragma unroll
    for (int p = 0; p < 16; ++p) S[p] = ae * (S[p] + m[p]);
  }
}

// ---------------- scan Y: A = causal(kA · kIA^T); y = A·V + kA·S0; out y*r ----------------
__global__ __launch_bounds__(256) void scan_y(
    const ushort* __restrict__ kA, const ushort* __restrict__ kIA,
    const ushort* __restrict__ vb, const ushort* __restrict__ rb,
    const char* __restrict__ McBase, ushort* __restrict__ yrow) {
  __shared__ __align__(16) ushort kAt[TC * PA];
  __shared__ __align__(16) ushort kIAt[TC * PA];
  __shared__ __align__(16) ushort Vt[TC * PV];
  __shared__ __align__(16) ushort S0t[TC * PV];
  __shared__ __align__(16) ushort Am[TC * PA];
  const int bh = blockIdx.x, c = blockIdx.y;
  const int b = bh / H_, h = bh % H_;
  const int tid = threadIdx.x;
  const int w = tid >> 6, lane = tid & 63;
  const int fr = lane & 15, fq = lane >> 4;
  {
    const int row = tid >> 2, col = (tid & 3) * 16;
    const ushort* gka = kA + ((size_t)bh * T_ + (size_t)c * TC + row) * HS_ + col;
    const ushort* gki = kIA + ((size_t)bh * T_ + (size_t)c * TC + row) * HS_ + col;
    const ushort* gv = vb + ((size_t)b * T_ + (size_t)c * TC + row) * D_ + h * HS_ + col;
    const ushort* gs = (const ushort*)(McBase + ((size_t)bh * NC + c) * 16384) + row * HS_ + col;
    uint4 a0 = *(const uint4*)gka; uint4 a1 = *(const uint4*)(gka + 8);
    uint4 i0 = *(const uint4*)gki; uint4 i1 = *(const uint4*)(gki + 8);
    uint4 v0 = *(const uint4*)gv;  uint4 v1 = *(const uint4*)(gv + 8);
    uint4 s0 = *(const uint4*)gs;  uint4 s1 = *(const uint4*)(gs + 8);
    *(uint4*)&kAt[row * PA + col] = a0;
    *(uint4*)&kAt[row * PA + col + 8] = a1;
    *(uint4*)&kIAt[row * PA + col] = i0;
    *(uint4*)&kIAt[row * PA + col + 8] = i1;
    ushort* pv = Vt + row * PV + col;
    *(uint2*)(pv + 0) = make_uint2(v0.x, v0.y);
    *(uint2*)(pv + 4) = make_uint2(v0.z, v0.w);
    *(uint2*)(pv + 8) = make_uint2(v1.x, v1.y);
    *(uint2*)(pv + 12) = make_uint2(v1.z, v1.w);
    ushort* ps = S0t + row * PV + col;
    *(uint2*)(ps + 0) = make_uint2(s0.x, s0.y);
    *(uint2*)(ps + 4) = make_uint2(s0.z, s0.w);
    *(uint2*)(ps + 8) = make_uint2(s1.x, s1.y);
    *(uint2*)(ps + 12) = make_uint2(s1.z, s1.w);
  }
  __syncthreads();

  f32x4 zero = {0.f, 0.f, 0.f, 0.f};
  // ---- phase A: A[t][s] = sum_i kA[t][i]*kIA[s][i], rows w*16..w*16+15 ----
  {
    f32x4 accA[4] = {zero, zero, zero, zero};
#pragma unroll
    for (int kk = 0; kk < 2; ++kk) {
      bf16x8 af = *reinterpret_cast<const bf16x8*>(&kAt[(w * 16 + fr) * PA + kk * 32 + fq * 8]);
#pragma unroll
      for (int nf = 0; nf < 4; ++nf) {
        bf16x8 b8 = *reinterpret_cast<const bf16x8*>(&kIAt[(nf * 16 + fr) * PA + kk * 32 + fq * 8]);
        accA[nf] = __builtin_amdgcn_mfma_f32_16x16x32_bf16(af, b8, accA[nf], 0, 0, 0);
      }
    }
#pragma unroll
    for (int nf = 0; nf < 4; ++nf)
#pragma unroll
      for (int rr = 0; rr < 4; ++rr) {
        int t = w * 16 + fq * 4 + rr;
        int s = nf * 16 + fr;
        float val = (s <= t) ? accA[nf][rr] : 0.f;
        Am[t * PA + s] = f2bf(val);
      }
  }
  __syncthreads();

  // ---- phase B: Y[t][j] = sum_i kA[t][i]*S0[i][j] + sum_s Am[t][s]*V[s][j] ----
  f32x4 accY[4] = {zero, zero, zero, zero};
#pragma unroll
  for (int kk = 0; kk < 2; ++kk) {
    bf16x8 af = *reinterpret_cast<const bf16x8*>(&kAt[(w * 16 + fr) * PA + kk * 32 + fq * 8]);
#pragma unroll
    for (int nf = 0; nf < 4; ++nf) {
      bf16x8 b8 = ldsT68(S0t, kk * 32 + fq * 8, nf * 16 + fr);
      accY[nf] = __builtin_amdgcn_mfma_f32_16x16x32_bf16(af, b8, accY[nf], 0, 0, 0);
    }
  }
#pragma unroll
  for (int kk = 0; kk < 2; ++kk) {
    bf16x8 af = *reinterpret_cast<const bf16x8*>(&Am[(w * 16 + fr) * PA + kk * 32 + fq * 8]);
#pragma unroll
    for (int nf = 0; nf < 4; ++nf) {
      bf16x8 b8 = ldsT68(Vt, kk * 32 + fq * 8, nf * 16 + fr);
      accY[nf] = __builtin_amdgcn_mfma_f32_16x16x32_bf16(af, b8, accY[nf], 0, 0, 0);
    }
  }
#pragma unroll
  for (int nf = 0; nf < 4; ++nf)
#pragma unroll
    for (int rr = 0; rr < 4; ++rr) {
      int t = w * 16 + fq * 4 + rr;
      int j = nf * 16 + fr;
      size_t go = ((size_t)b * T_ + (size_t)c * TC + t) * D_ + h * HS_ + j;
      float rv = bf2f(rb[go]);
      yrow[go] = f2bf(accY[nf][rr] * rv);
    }
}

// ---------------- launch ----------------
extern "C" void kernel_launch(void* const* d_in, const int* in_sizes, int n_in,
                              void* d_out, int out_size, void* d_ws, size_t ws_size,
                              hipStream_t stream) {
  const float* x     = (const float*)d_in[0];
  const float* Wx    = (const float*)d_in[1];
  const float* Ww    = (const float*)d_in[2];
  const float* bw    = (const float*)d_in[3];
  const float* Wk    = (const float*)d_in[4];
  const float* Wv    = (const float*)d_in[5];
  const float* Wr    = (const float*)d_in[6];
  const float* Wo    = (const float*)d_in[7];
  const float* gamma = (const float*)d_in[8];
  const float* beta  = (const float*)d_in[9];
  float* out = (float*)d_out;

  // workspace (bytes), NEED = 208404480 (proven round 3/4):
  //   xn  [0,          25165824)  bf16  -> reused: kA   (prep out)
  //   wb  [25165824,   32243712)  bf16  Wcat(k,v,r,x) + Ww + Wo
  //   xp  [32243712,   57409536)  bf16  -> reused: kIA  (prep out)
  //   kb  [57409536,   82575360)  bf16
  //   vb  [82575360,  107741184)  bf16
  //   rb  [107741184, 132907008)  bf16
  //   yr  [132907008, 158072832)  bf16  (head doubles as aend fp32 786KB pre-scan_y)
  //   df  [158072832, 208404480)  fp32  -> reused: Mc slots (16KB per bh,c; S0 bf16 in first 8KB)
  const size_t NEED = 208404480ull;
  if (ws_size < NEED) {
    zero_out_kernel<<<2048, 256, 0, stream>>>(out, out_size);
    return;
  }

  char* ws = (char*)d_ws;
  ushort* xn = (ushort*)ws;
  ushort* wb = (ushort*)(ws + 25165824);
  ushort* xp = (ushort*)(ws + 32243712);
  ushort* kb = (ushort*)(ws + 57409536);
  ushort* vb = (ushort*)(ws + 82575360);
  ushort* rb = (ushort*)(ws + 107741184);
  ushort* yr = (ushort*)(ws + 132907008);
  float*  df = (float*)(ws + 158072832);
  ushort* kAb  = (ushort*)ws;              // aliases xn (dead after gemm_cat)
  ushort* kIAb = (ushort*)(ws + 32243712); // aliases xp (dead after decay gemm)
  float*  aendb = (float*)(ws + 132907008);// yr head (overwritten later by scan_y)
  char*   McBase = (char*)(ws + 158072832);// aliases df (dead after prep)

  ushort* WcatB = wb;                      // rows: [Wk; Wv; Wr; Wx]
  ushort* WwB = wb + 4 * 589824;
  ushort* WoB = wb + 5 * 589824;

  cast_w_kernel<<<576, 256, 0, stream>>>(Wk, WcatB);
  cast_w_kernel<<<576, 256, 0, stream>>>(Wv, WcatB + 589824);
  cast_w_kernel<<<576, 256, 0, stream>>>(Wr, WcatB + 2 * 589824);
  cast_w_kernel<<<576, 256, 0, stream>>>(Wx, WcatB + 3 * 589824);
  cast_w_kernel<<<576, 256, 0, stream>>>(Ww, WwB);
  cast_w_kernel<<<576, 256, 0, stream>>>(Wo, WoB);
  ln_kernel<<<4096, 256, 0, stream>>>(x, gamma, beta, xn);

  gemm_cat<<<dim3(128, 24), 256, 0, stream>>>(xn, WcatB, kb, vb, rb, xp);
  gemm_bt<<<dim3(128, 6), 256, 0, stream>>>(xp, WwB, df, bw, 3);  // decay fp32

  scan_prep<<<dim3(96, NC), 64, 0, stream>>>(kb, df, kAb, kIAb, aendb);
  scan_mc<<<dim3(96, NC), 256, 0, stream>>>(kIAb, vb, McBase);
  scan_chain<<<96, 256, 0, stream>>>(McBase, aendb);
  scan_y<<<dim3(96, NC), 256, 0, stream>>>(kAb, kIAb, vb, rb, McBase, yr);

  gemm_bt<<<dim3(128, 6), 256, 0, stream>>>(yr, WoB, out, nullptr, 0);  // final
}

// Round 6
// 277.585 us; speedup vs baseline: 3.7870x; 1.2938x over previous
//
#include <hip/hip_runtime.h>

#define B_ 8
#define T_ 2048
#define D_ 768
#define H_ 12
#define HS_ 64
#define LN_EPS 1e-5f
#define NC 32   // chunks
#define TC 64   // timesteps per chunk
#define PA 72   // LDS pitch (halves) for row-read tiles
#define PV 68   // LDS pitch (halves) for transposed-read tiles

typedef __attribute__((ext_vector_type(8))) short bf16x8;
typedef __attribute__((ext_vector_type(4))) float f32x4;

__device__ __forceinline__ ushort f2bf(float f) {
  unsigned u = __builtin_bit_cast(unsigned, f);
  unsigned r = (u + 0x7FFFu + ((u >> 16) & 1u)) >> 16;
  return (ushort)r;
}
__device__ __forceinline__ float bf2f(ushort u) {
  return __builtin_bit_cast(float, ((unsigned)u) << 16);
}

__device__ __forceinline__ bf16x8 ldsT68(const ushort* tile, int r0, int col) {
  bf16x8 r;
#pragma unroll
  for (int e = 0; e < 8; ++e) r[e] = (short)tile[(r0 + e) * PV + col];
  return r;
}

// ---------------- canary ----------------
__global__ __launch_bounds__(256) void zero_out_kernel(float* __restrict__ out, int n) {
  for (int i = blockIdx.x * 256 + threadIdx.x; i < n; i += gridDim.x * 256)
    out[i] = 0.f;
}

// ---------------- weight cast ----------------
__global__ __launch_bounds__(256) void cast_w_kernel(
    const float* __restrict__ src, ushort* __restrict__ dst) {
  int idx = (blockIdx.x * 256 + threadIdx.x) * 4;
  float4 v = *reinterpret_cast<const float4*>(src + idx);
  ushort4 o;
  o.x = f2bf(v.x); o.y = f2bf(v.y); o.z = f2bf(v.z); o.w = f2bf(v.w);
  *reinterpret_cast<ushort4*>(dst + idx) = o;
}

// ---------------- LayerNorm ----------------
__global__ __launch_bounds__(256) void ln_kernel(
    const float* __restrict__ x, const float* __restrict__ gamma,
    const float* __restrict__ beta, ushort* __restrict__ xn) {
  const int wv = threadIdx.x >> 6;
  const int lane = threadIdx.x & 63;
  const int row = blockIdx.x * 4 + wv;
  const float* xr = x + (size_t)row * D_;
  float4 a[3];
#pragma unroll
  for (int s = 0; s < 3; ++s)
    a[s] = *reinterpret_cast<const float4*>(xr + s * 256 + lane * 4);
  float sum = 0.f;
#pragma unroll
  for (int s = 0; s < 3; ++s) sum += a[s].x + a[s].y + a[s].z + a[s].w;
#pragma unroll
  for (int off = 32; off; off >>= 1) sum += __shfl_xor(sum, off);
  float mu = sum * (1.f / 768.f);
  float vs = 0.f;
#pragma unroll
  for (int s = 0; s < 3; ++s) {
    float dx = a[s].x - mu, dy = a[s].y - mu, dz = a[s].z - mu, dw = a[s].w - mu;
    vs += dx * dx + dy * dy + dz * dz + dw * dw;
  }
#pragma unroll
  for (int off = 32; off; off >>= 1) vs += __shfl_xor(vs, off);
  float rs = rsqrtf(vs * (1.f / 768.f) + LN_EPS);
  ushort* orow = xn + (size_t)row * D_;
#pragma unroll
  for (int s = 0; s < 3; ++s) {
    int col = s * 256 + lane * 4;
    float4 g = *reinterpret_cast<const float4*>(gamma + col);
    float4 bb = *reinterpret_cast<const float4*>(beta + col);
    ushort4 o;
    o.x = f2bf((a[s].x - mu) * rs * g.x + bb.x);
    o.y = f2bf((a[s].y - mu) * rs * g.y + bb.y);
    o.z = f2bf((a[s].z - mu) * rs * g.z + bb.z);
    o.w = f2bf((a[s].w - mu) * rs * g.w + bb.w);
    *reinterpret_cast<ushort4*>(orow + col) = o;
  }
}

// ---------------- 256x256 8-phase bf16 MFMA GEMM ----------------
// C[m,n] = sum_k A[m,k]*W[n,k].  K=768 fixed. 512 threads = 8 waves (2M x 4N).
// LDS: 8 half-regions of 16KB: [buf][A/B][half][128][64] bf16, XOR-swizzled blocks.
// modes: 0 fp32 plain, 3 fp32 decay=1-sigmoid(val+bias), 5 cat->4 bf16 dests (sigmoid on #2)
__global__ __launch_bounds__(512, 2) void gemm256(
    const ushort* __restrict__ A, const ushort* __restrict__ W,
    float* __restrict__ Cf,
    ushort* __restrict__ d0, ushort* __restrict__ d1,
    ushort* __restrict__ d2, ushort* __restrict__ d3,
    const float* __restrict__ bias, int mode) {
  __shared__ __align__(16) ushort lds[65536];  // 128 KiB
  const int tid = threadIdx.x;
  const int wid = tid >> 6;
  const int lane = tid & 63;
  const int wr = wid >> 2, wc = wid & 3;
  const int fr = lane & 15, fq = lane >> 4;
  const int m0 = blockIdx.x * 256, n0 = blockIdx.y * 256;
  const int strow = tid >> 3;  // 0..63
  const int stblk = tid & 7;

  // read-region bases (ushort units)
  const int RA0 = wr * 8192;
  const int RA1 = 32768 + wr * 8192;
  const int RB0 = 16384 + (wc >> 1) * 8192 + (wc & 1) * 4096;
  const int RB1 = 49152 + (wc >> 1) * 8192 + (wc & 1) * 4096;

  f32x4 acc[8][4];
#pragma unroll
  for (int m = 0; m < 8; ++m)
#pragma unroll
    for (int n = 0; n < 4; ++n) acc[m][n] = (f32x4){0.f, 0.f, 0.f, 0.f};

// stage one 128x64 half-tile (16KB): linear LDS dest, inverse-swizzled global src
#define STAGE_HALF(gb, grow0, kk0, roff)                                          \
  {                                                                               \
    _Pragma("unroll") for (int j = 0; j < 2; ++j) {                               \
      const int lr_ = j * 64 + strow;                                             \
      const int bs_ = stblk ^ (lr_ & 7);                                          \
      const ushort* s_ = (gb) + (size_t)((grow0) + lr_) * 768 + (kk0) + bs_ * 8;  \
      __builtin_amdgcn_global_load_lds(                                           \
          (const __attribute__((address_space(1))) void*)s_,                      \
          (__attribute__((address_space(3))) void*)(lds + (roff) + j * 4096 + wid * 512), \
          16, 0, 0);                                                              \
    }                                                                             \
  }

// swizzled fragment read (b128)
#define LDF(dst, base, rf, kk)                                                    \
  dst = *reinterpret_cast<const bf16x8*>(                                         \
      lds + (base) + ((rf)*16 + fr) * 64 + ((((kk)*4 + fq) ^ (fr & 7)) * 8));

#define MFMA_Q(mb, nb, aa, bb)                                                    \
  __builtin_amdgcn_s_setprio(1);                                                  \
  _Pragma("unroll") for (int m_ = 0; m_ < 4; ++m_)                                \
  _Pragma("unroll") for (int n_ = 0; n_ < 2; ++n_)                                \
  _Pragma("unroll") for (int k_ = 0; k_ < 2; ++k_)                                \
    acc[(mb) + m_][(nb) + n_] = __builtin_amdgcn_mfma_f32_16x16x32_bf16(          \
        aa[m_][k_], bb[n_][k_], acc[(mb) + m_][(nb) + n_], 0, 0, 0);              \
  __builtin_amdgcn_s_setprio(0);

  // ---- prologue: stage tile0 (A+B) and B(tile1) ----
  STAGE_HALF(A, m0, 0, 0);
  STAGE_HALF(A, m0 + 128, 0, 8192);
  STAGE_HALF(W, n0, 0, 16384);
  STAGE_HALF(W, n0 + 128, 0, 24576);
  STAGE_HALF(W, n0, 64, 49152);
  STAGE_HALF(W, n0 + 128, 64, 57344);
  asm volatile("s_waitcnt vmcnt(4)" ::: "memory");
  __builtin_amdgcn_s_barrier();

  bf16x8 aL[4][2], aH[4][2], bL[2][2], bH[2][2];

  for (int i = 0; i < 6; ++i) {
    const int kQ = (2 * i + 1) * 64;                       // tile 2i+1 (always real)
    const int kP2 = (2 * i + 2 <= 11 ? 2 * i + 2 : 11) * 64;
    const int kQ2 = (2 * i + 3 <= 11 ? 2 * i + 3 : 11) * 64;

    // ======== tile P = 2i (buf0) ========
    // ph1: stage A(Q)h0 -> Abuf1h0
    STAGE_HALF(A, m0, kQ, 32768);
#pragma unroll
    for (int m = 0; m < 4; ++m) { LDF(aL[m][0], RA0, m, 0); LDF(aL[m][1], RA0, m, 1); }
#pragma unroll
    for (int n = 0; n < 2; ++n) { LDF(bL[n][0], RB0, n, 0); LDF(bL[n][1], RB0, n, 1); }
    __builtin_amdgcn_s_barrier();
    MFMA_Q(0, 0, aL, bL);
    __builtin_amdgcn_s_barrier();
    // ph2: stage A(Q)h1
    STAGE_HALF(A, m0 + 128, kQ, 40960);
#pragma unroll
    for (int n = 0; n < 2; ++n) { LDF(bH[n][0], RB0, n + 2, 0); LDF(bH[n][1], RB0, n + 2, 1); }
    __builtin_amdgcn_s_barrier();
    MFMA_Q(0, 2, aL, bH);
    __builtin_amdgcn_s_barrier();
    // ph3: stage B(P+2)h0 -> Bbuf0h0 (free since ph2)
    STAGE_HALF(W, n0, kP2, 16384);
#pragma unroll
    for (int m = 0; m < 4; ++m) { LDF(aH[m][0], RA0, m + 4, 0); LDF(aH[m][1], RA0, m + 4, 1); }
    __builtin_amdgcn_s_barrier();
    MFMA_Q(4, 0, aH, bL);
    __builtin_amdgcn_s_barrier();
    // ph4: stage B(P+2)h1
    STAGE_HALF(W, n0 + 128, kP2, 24576);
    __builtin_amdgcn_s_barrier();
    MFMA_Q(4, 2, aH, bH);
    asm volatile("s_waitcnt vmcnt(4)" ::: "memory");  // tile Q fully landed
    __builtin_amdgcn_s_barrier();

    // ======== tile Q = 2i+1 (buf1) ========
    // ph5: stage A(P+2)h0 -> Abuf0h0 (free since ph3)
    STAGE_HALF(A, m0, kP2, 0);
#pragma unroll
    for (int m = 0; m < 4; ++m) { LDF(aL[m][0], RA1, m, 0); LDF(aL[m][1], RA1, m, 1); }
#pragma unroll
    for (int n = 0; n < 2; ++n) { LDF(bL[n][0], RB1, n, 0); LDF(bL[n][1], RB1, n, 1); }
    __builtin_amdgcn_s_barrier();
    MFMA_Q(0, 0, aL, bL);
    __builtin_amdgcn_s_barrier();
    // ph6: stage A(P+2)h1
    STAGE_HALF(A, m0 + 128, kP2, 8192);
#pragma unroll
    for (int n = 0; n < 2; ++n) { LDF(bH[n][0], RB1, n + 2, 0); LDF(bH[n][1], RB1, n + 2, 1); }
    __builtin_amdgcn_s_barrier();
    MFMA_Q(0, 2, aL, bH);
    __builtin_amdgcn_s_barrier();
    // ph7: stage B(Q+2)h0 -> Bbuf1h0 (free since ph6)
    STAGE_HALF(W, n0, kQ2, 49152);
#pragma unroll
    for (int m = 0; m < 4; ++m) { LDF(aH[m][0], RA1, m + 4, 0); LDF(aH[m][1], RA1, m + 4, 1); }
    __builtin_amdgcn_s_barrier();
    MFMA_Q(4, 0, aH, bL);
    __builtin_amdgcn_s_barrier();
    // ph8: stage B(Q+2)h1
    STAGE_HALF(W, n0 + 128, kQ2, 57344);
    __builtin_amdgcn_s_barrier();
    MFMA_Q(4, 2, aH, bH);
    asm volatile("s_waitcnt vmcnt(4)" ::: "memory");  // tile P+2 fully landed
    __builtin_amdgcn_s_barrier();
  }

  // ---- epilogue ----
  const int r0 = fq * 4;
  if (mode == 5) {
    const int sel = n0 >= 2304 ? 3 : n0 >= 1536 ? 2 : n0 >= 768 ? 1 : 0;
    ushort* dst = sel == 0 ? d0 : sel == 1 ? d1 : sel == 2 ? d2 : d3;
    const int nb = n0 - sel * 768;
    const bool sig = (sel == 2);
#pragma unroll
    for (int mf = 0; mf < 8; ++mf)
#pragma unroll
      for (int nf = 0; nf < 4; ++nf) {
        int gr = m0 + wr * 128 + mf * 16 + r0;
        int gc = nb + wc * 64 + nf * 16 + fr;
#pragma unroll
        for (int rr = 0; rr < 4; ++rr) {
          float v = acc[mf][nf][rr];
          if (sig) v = 1.f / (1.f + __expf(-v));
          dst[(size_t)(gr + rr) * 768 + gc] = f2bf(v);
        }
      }
  } else if (mode == 3) {
#pragma unroll
    for (int mf = 0; mf < 8; ++mf)
#pragma unroll
      for (int nf = 0; nf < 4; ++nf) {
        int gr = m0 + wr * 128 + mf * 16 + r0;
        int gc = n0 + wc * 64 + nf * 16 + fr;
        float bv = bias[gc];
#pragma unroll
        for (int rr = 0; rr < 4; ++rr) {
          float u = acc[mf][nf][rr] + bv;
          Cf[(size_t)(gr + rr) * 768 + gc] = 1.f / (1.f + __expf(u));
        }
      }
  } else {
#pragma unroll
    for (int mf = 0; mf < 8; ++mf)
#pragma unroll
      for (int nf = 0; nf < 4; ++nf) {
        int gr = m0 + wr * 128 + mf * 16 + r0;
        int gc = n0 + wc * 64 + nf * 16 + fr;
#pragma unroll
        for (int rr = 0; rr < 4; ++rr)
          Cf[(size_t)(gr + rr) * 768 + gc] = acc[mf][nf][rr];
      }
  }
#undef STAGE_HALF
#undef LDF
#undef MFMA_Q
}

// ---------------- scan prep: cumulative decay products per chunk ----------------
__global__ __launch_bounds__(64) void scan_prep(
    const ushort* __restrict__ kb, const float* __restrict__ dg,
    ushort* __restrict__ kA, ushort* __restrict__ kIA, float* __restrict__ aend) {
  const int bh = blockIdx.x, c = blockIdx.y;
  const int b = bh / H_, h = bh % H_;
  const int i = threadIdx.x;
  size_t go = (size_t)b * T_ * D_ + (size_t)(c * TC) * D_ + h * HS_ + i;
  size_t co = ((size_t)bh * T_ + (size_t)c * TC) * HS_ + i;
  float a = 1.f;
#pragma unroll 4
  for (int t = 0; t < TC; ++t) {
    float d = dg[go];
    float k = bf2f(kb[go]);
    a *= d;
    kA[co] = f2bf(k * a);
    kIA[co] = f2bf(k / a);
    go += D_;
    co += HS_;
  }
  aend[((size_t)bh * NC + c) * HS_ + i] = a;
}

// ---------------- scan Mc: Mc[i][j] = sum_s kIA[s][i] * V[s][j] ----------------
__global__ __launch_bounds__(256) void scan_mc(
    const ushort* __restrict__ kIA, const ushort* __restrict__ vb,
    char* __restrict__ McBase) {
  __shared__ __align__(16) ushort kt[TC * PV];
  __shared__ __align__(16) ushort vt[TC * PV];
  const int bh = blockIdx.x, c = blockIdx.y;
  const int b = bh / H_, h = bh % H_;
  const int tid = threadIdx.x;
  const int w = tid >> 6, lane = tid & 63;
  const int fr = lane & 15, fq = lane >> 4;
  {
    const int row = tid >> 2, col = (tid & 3) * 16;
    const ushort* gki = kIA + ((size_t)bh * T_ + (size_t)c * TC + row) * HS_ + col;
    const ushort* gv = vb + ((size_t)b * T_ + (size_t)c * TC + row) * D_ + h * HS_ + col;
    uint4 i0 = *(const uint4*)gki; uint4 i1 = *(const uint4*)(gki + 8);
    uint4 v0 = *(const uint4*)gv;  uint4 v1 = *(const uint4*)(gv + 8);
    ushort* pk = kt + row * PV + col;
    *(uint2*)(pk + 0) = make_uint2(i0.x, i0.y);
    *(uint2*)(pk + 4) = make_uint2(i0.z, i0.w);
    *(uint2*)(pk + 8) = make_uint2(i1.x, i1.y);
    *(uint2*)(pk + 12) = make_uint2(i1.z, i1.w);
    ushort* pv = vt + row * PV + col;
    *(uint2*)(pv + 0) = make_uint2(v0.x, v0.y);
    *(uint2*)(pv + 4) = make_uint2(v0.z, v0.w);
    *(uint2*)(pv + 8) = make_uint2(v1.x, v1.y);
    *(uint2*)(pv + 12) = make_uint2(v1.z, v1.w);
  }
  __syncthreads();
  f32x4 zero = {0.f, 0.f, 0.f, 0.f};
  f32x4 acc[4] = {zero, zero, zero, zero};
#pragma unroll
  for (int kk = 0; kk < 2; ++kk) {
    bf16x8 af = ldsT68(kt, kk * 32 + fq * 8, w * 16 + fr);
#pragma unroll
    for (int nf = 0; nf < 4; ++nf) {
      bf16x8 b8 = ldsT68(vt, kk * 32 + fq * 8, nf * 16 + fr);
      acc[nf] = __builtin_amdgcn_mfma_f32_16x16x32_bf16(af, b8, acc[nf], 0, 0, 0);
    }
  }
  float* mc = (float*)(McBase + ((size_t)bh * NC + c) * 16384);
#pragma unroll
  for (int nf = 0; nf < 4; ++nf)
#pragma unroll
    for (int rr = 0; rr < 4; ++rr) {
      int i = w * 16 + fq * 4 + rr, j = nf * 16 + fr;
      mc[i * 64 + j] = acc[nf][rr];
    }
}

// ---------------- scan chain ----------------
__global__ __launch_bounds__(256) void scan_chain(
    char* __restrict__ McBase, const float* __restrict__ aend) {
  const int bh = blockIdx.x;
  const int i = threadIdx.x >> 2, j0 = (threadIdx.x & 3) * 16;
  float S[16];
#pragma unroll
  for (int p = 0; p < 16; ++p) S[p] = 0.f;
  for (int c = 0; c < NC; ++c) {
    char* slot = McBase + ((size_t)bh * NC + c) * 16384;
    const float* mc = (const float*)slot + i * 64 + j0;
    float m[16];
#pragma unroll
    for (int p = 0; p < 16; ++p) m[p] = mc[p];
    __syncthreads();
    ushort* s0 = (ushort*)slot + i * 64 + j0;
#pragma unroll
    for (int p = 0; p < 16; ++p) s0[p] = f2bf(S[p]);
    float ae = aend[((size_t)bh * NC + c) * HS_ + i];
#pragma unroll
    for (int p = 0; p < 16; ++p) S[p] = ae * (S[p] + m[p]);
  }
}

// ---------------- scan Y ----------------
__global__ __launch_bounds__(256) void scan_y(
    const ushort* __restrict__ kA, const ushort* __restrict__ kIA,
    const ushort* __restrict__ vb, const ushort* __restrict__ rb,
    const char* __restrict__ McBase, ushort* __restrict__ yrow) {
  __shared__ __align__(16) ushort kAt[TC * PA];
  __shared__ __align__(16) ushort kIAt[TC * PA];
  __shared__ __align__(16) ushort Vt[TC * PV];
  __shared__ __align__(16) ushort S0t[TC * PV];
  __shared__ __align__(16) ushort Am[TC * PA];
  const int bh = blockIdx.x, c = blockIdx.y;
  const int b = bh / H_, h = bh % H_;
  const int tid = threadIdx.x;
  const int w = tid >> 6, lane = tid & 63;
  const int fr = lane & 15, fq = lane >> 4;
  {
    const int row = tid >> 2, col = (tid & 3) * 16;
    const ushort* gka = kA + ((size_t)bh * T_ + (size_t)c * TC + row) * HS_ + col;
    const ushort* gki = kIA + ((size_t)bh * T_ + (size_t)c * TC + row) * HS_ + col;
    const ushort* gv = vb + ((size_t)b * T_ + (size_t)c * TC + row) * D_ + h * HS_ + col;
    const ushort* gs = (const ushort*)(McBase + ((size_t)bh * NC + c) * 16384) + row * HS_ + col;
    uint4 a0 = *(const uint4*)gka; uint4 a1 = *(const uint4*)(gka + 8);
    uint4 i0 = *(const uint4*)gki; uint4 i1 = *(const uint4*)(gki + 8);
    uint4 v0 = *(const uint4*)gv;  uint4 v1 = *(const uint4*)(gv + 8);
    uint4 s0 = *(const uint4*)gs;  uint4 s1 = *(const uint4*)(gs + 8);
    *(uint4*)&kAt[row * PA + col] = a0;
    *(uint4*)&kAt[row * PA + col + 8] = a1;
    *(uint4*)&kIAt[row * PA + col] = i0;
    *(uint4*)&kIAt[row * PA + col + 8] = i1;
    ushort* pv = Vt + row * PV + col;
    *(uint2*)(pv + 0) = make_uint2(v0.x, v0.y);
    *(uint2*)(pv + 4) = make_uint2(v0.z, v0.w);
    *(uint2*)(pv + 8) = make_uint2(v1.x, v1.y);
    *(uint2*)(pv + 12) = make_uint2(v1.z, v1.w);
    ushort* ps = S0t + row * PV + col;
    *(uint2*)(ps + 0) = make_uint2(s0.x, s0.y);
    *(uint2*)(ps + 4) = make_uint2(s0.z, s0.w);
    *(uint2*)(ps + 8) = make_uint2(s1.x, s1.y);
    *(uint2*)(ps + 12) = make_uint2(s1.z, s1.w);
  }
  __syncthreads();

  f32x4 zero = {0.f, 0.f, 0.f, 0.f};
  {
    f32x4 accA[4] = {zero, zero, zero, zero};
#pragma unroll
    for (int kk = 0; kk < 2; ++kk) {
      bf16x8 af = *reinterpret_cast<const bf16x8*>(&kAt[(w * 16 + fr) * PA + kk * 32 + fq * 8]);
#pragma unroll
      for (int nf = 0; nf < 4; ++nf) {
        bf16x8 b8 = *reinterpret_cast<const bf16x8*>(&kIAt[(nf * 16 + fr) * PA + kk * 32 + fq * 8]);
        accA[nf] = __builtin_amdgcn_mfma_f32_16x16x32_bf16(af, b8, accA[nf], 0, 0, 0);
      }
    }
#pragma unroll
    for (int nf = 0; nf < 4; ++nf)
#pragma unroll
      for (int rr = 0; rr < 4; ++rr) {
        int t = w * 16 + fq * 4 + rr;
        int s = nf * 16 + fr;
        float val = (s <= t) ? accA[nf][rr] : 0.f;
        Am[t * PA + s] = f2bf(val);
      }
  }
  __syncthreads();

  f32x4 accY[4] = {zero, zero, zero, zero};
#pragma unroll
  for (int kk = 0; kk < 2; ++kk) {
    bf16x8 af = *reinterpret_cast<const bf16x8*>(&kAt[(w * 16 + fr) * PA + kk * 32 + fq * 8]);
#pragma unroll
    for (int nf = 0; nf < 4; ++nf) {
      bf16x8 b8 = ldsT68(S0t, kk * 32 + fq * 8, nf * 16 + fr);
      accY[nf] = __builtin_amdgcn_mfma_f32_16x16x32_bf16(af, b8, accY[nf], 0, 0, 0);
    }
  }
#pragma unroll
  for (int kk = 0; kk < 2; ++kk) {
    bf16x8 af = *reinterpret_cast<const bf16x8*>(&Am[(w * 16 + fr) * PA + kk * 32 + fq * 8]);
#pragma unroll
    for (int nf = 0; nf < 4; ++nf) {
      bf16x8 b8 = ldsT68(Vt, kk * 32 + fq * 8, nf * 16 + fr);
      accY[nf] = __builtin_amdgcn_mfma_f32_16x16x32_bf16(af, b8, accY[nf], 0, 0, 0);
    }
  }
#pragma unroll
  for (int nf = 0; nf < 4; ++nf)
#pragma unroll
    for (int rr = 0; rr < 4; ++rr) {
      int t = w * 16 + fq * 4 + rr;
      int j = nf * 16 + fr;
      size_t go = ((size_t)b * T_ + (size_t)c * TC + t) * D_ + h * HS_ + j;
      float rv = bf2f(rb[go]);
      yrow[go] = f2bf(accY[nf][rr] * rv);
    }
}

// ---------------- launch ----------------
extern "C" void kernel_launch(void* const* d_in, const int* in_sizes, int n_in,
                              void* d_out, int out_size, void* d_ws, size_t ws_size,
                              hipStream_t stream) {
  const float* x     = (const float*)d_in[0];
  const float* Wx    = (const float*)d_in[1];
  const float* Ww    = (const float*)d_in[2];
  const float* bw    = (const float*)d_in[3];
  const float* Wk    = (const float*)d_in[4];
  const float* Wv    = (const float*)d_in[5];
  const float* Wr    = (const float*)d_in[6];
  const float* Wo    = (const float*)d_in[7];
  const float* gamma = (const float*)d_in[8];
  const float* beta  = (const float*)d_in[9];
  float* out = (float*)d_out;

  const size_t NEED = 208404480ull;
  if (ws_size < NEED) {
    zero_out_kernel<<<2048, 256, 0, stream>>>(out, out_size);
    return;
  }

  char* ws = (char*)d_ws;
  ushort* xn = (ushort*)ws;
  ushort* wb = (ushort*)(ws + 25165824);
  ushort* xp = (ushort*)(ws + 32243712);
  ushort* kb = (ushort*)(ws + 57409536);
  ushort* vb = (ushort*)(ws + 82575360);
  ushort* rb = (ushort*)(ws + 107741184);
  ushort* yr = (ushort*)(ws + 132907008);
  float*  df = (float*)(ws + 158072832);
  ushort* kAb  = (ushort*)ws;               // aliases xn (dead after gemm_cat)
  ushort* kIAb = (ushort*)(ws + 32243712);  // aliases xp (dead after decay gemm)
  float*  aendb = (float*)(ws + 132907008); // yr head (overwritten later by scan_y)
  char*   McBase = (char*)(ws + 158072832); // aliases df (dead after prep)

  ushort* WcatB = wb;  // rows: [Wk; Wv; Wr; Wx]
  ushort* WwB = wb + 4 * 589824;
  ushort* WoB = wb + 5 * 589824;

  cast_w_kernel<<<576, 256, 0, stream>>>(Wk, WcatB);
  cast_w_kernel<<<576, 256, 0, stream>>>(Wv, WcatB + 589824);
  cast_w_kernel<<<576, 256, 0, stream>>>(Wr, WcatB + 2 * 589824);
  cast_w_kernel<<<576, 256, 0, stream>>>(Wx, WcatB + 3 * 589824);
  cast_w_kernel<<<576, 256, 0, stream>>>(Ww, WwB);
  cast_w_kernel<<<576, 256, 0, stream>>>(Wo, WoB);
  ln_kernel<<<4096, 256, 0, stream>>>(x, gamma, beta, xn);

  // fused k/v/r/xp GEMM (N=3072): mode 5
  gemm256<<<dim3(64, 12), 512, 0, stream>>>(xn, WcatB, nullptr, kb, vb, rb, xp,
                                            nullptr, 5);
  // decay GEMM (N=768): mode 3
  gemm256<<<dim3(64, 3), 512, 0, stream>>>(xp, WwB, df, nullptr, nullptr, nullptr,
                                           nullptr, bw, 3);

  scan_prep<<<dim3(96, NC), 64, 0, stream>>>(kb, df, kAb, kIAb, aendb);
  scan_mc<<<dim3(96, NC), 256, 0, stream>>>(kIAb, vb, McBase);
  scan_chain<<<96, 256, 0, stream>>>(McBase, aendb);
  scan_y<<<dim3(96, NC), 256, 0, stream>>>(kAb, kIAb, vb, rb, McBase, yr);

  // final GEMM (N=768): mode 0
  gemm256<<<dim3(64, 3), 512, 0, stream>>>(yr, WoB, out, nullptr, nullptr, nullptr,
                                           nullptr, nullptr, 0);
}